// Round 6
// baseline (246.774 us; speedup 1.0000x reference)
//
#include <hip/hip_runtime.h>
#include <cstdint>
#include <math.h>

// ---------------------------------------------------------------------------
// CausalSelfAttention (B=4, T=2048, D=1024, H=16, Dh=64), fp32 in/out,
// bf16 MFMA compute internally.
// Pipeline: fused cast -> fused QKV GEMM (128x192 tile, NS=3, 80KB LDS ->
//           2 blocks/CU, 1024 blocks, 4-phase read-ahead w/ counted waits)
//           -> flash attention (key-split, round 5) -> output projection
//           (128x128, NS=2, 64KB LDS -> 2 blocks/CU, 512 blocks fully
//           resident).
//
// Round-6 rationale: QKV was 66us at 1 block/CU (Occupancy 19%) -- barrier
// convoys at 2 waves/SIMD left both MFMA (30%) and LDS pipes half idle.
// Shrinking BN to fit 2 blocks/CU (16 waves, 4/SIMD) lets cross-block
// overlap hide the phase gaps; smaller acc (48 vs 96 VGPR) fits the
// <=128-VGPR budget needed for 2-block occupancy (__launch_bounds__(512,4)).
// ---------------------------------------------------------------------------

typedef unsigned short u16;
typedef __bf16 bf16x8 __attribute__((ext_vector_type(8)));
typedef __bf16 bf16x4 __attribute__((ext_vector_type(4)));
typedef float f32x4 __attribute__((ext_vector_type(4)));

__device__ __forceinline__ u16 f32_bf16(float f) {  // round-nearest-even
  union { float f; uint32_t u; } c; c.f = f;
  uint32_t u = c.u;
  return (u16)((u + 0x7FFFu + ((u >> 16) & 1u)) >> 16);
}

__device__ __forceinline__ f32x4 mfma16(bf16x8 a, bf16x8 b, f32x4 c) {
  return __builtin_amdgcn_mfma_f32_16x16x32_bf16(a, b, c, 0, 0, 0);
}

// async global->LDS, 16B/lane. LDS dest must be wave-uniform base + lane*16.
__device__ __forceinline__ void gload_lds16(const u16* g, u16* l) {
  __builtin_amdgcn_global_load_lds(
      (const __attribute__((address_space(1))) void*)g,
      (__attribute__((address_space(3))) void*)l, 16, 0, 0);
}

template <int N>
__device__ __forceinline__ void wait_lgkm() {
  if (N == 0)      asm volatile("s_waitcnt lgkmcnt(0)" ::: "memory");
  else if (N == 6) asm volatile("s_waitcnt lgkmcnt(6)" ::: "memory");
  __builtin_amdgcn_sched_barrier(0);
}
template <int N>
__device__ __forceinline__ void wait_vm() {
  if (N == 5)      asm volatile("s_waitcnt vmcnt(5)" ::: "memory");
  else if (N == 4) asm volatile("s_waitcnt vmcnt(4)" ::: "memory");
  else if (N == 2) asm volatile("s_waitcnt vmcnt(2)" ::: "memory");
  else if (N == 0) asm volatile("s_waitcnt vmcnt(0)" ::: "memory");
  __builtin_amdgcn_sched_barrier(0);
}

// barrier that does NOT drain the newest 2 vm loads (attn t+2 prefetch)
__device__ __forceinline__ void barrier_vm2() {
  asm volatile("s_waitcnt vmcnt(2)" ::: "memory");
  __builtin_amdgcn_sched_barrier(0);
  __builtin_amdgcn_s_barrier();
}

// ---------------------------------------------------------------------------
// fused cast fp32->bf16 of x + 4 weights into contiguous ws region
// ---------------------------------------------------------------------------
__global__ __launch_bounds__(256) void cvt_all_kernel(
    const float* __restrict__ x,
    const float* __restrict__ wq, const float* __restrict__ wk,
    const float* __restrict__ wv, const float* __restrict__ wo,
    u16* __restrict__ dst, int n_x, int n_w) {
  int i = blockIdx.x * 256 + threadIdx.x;
  const float* src;
  int off;
  if (i < n_x) { src = x; off = i; }
  else {
    int j = i - n_x;
    int w = j / n_w;  off = j - w * n_w;
    src = (w == 0) ? wq : (w == 1) ? wk : (w == 2) ? wv : wo;
  }
  float4 f = ((const float4*)src)[off];
  ushort4 o;
  o.x = f32_bf16(f.x); o.y = f32_bf16(f.y);
  o.z = f32_bf16(f.z); o.w = f32_bf16(f.w);
  ((ushort4*)dst)[i] = o;
}

// ---------------------------------------------------------------------------
// 2-blocks/CU GEMM: C[m,n] = sum_k A[m,k]*B[n,k] (both K-contiguous).
// BM=128, BN=NS*64 (QKV NS=3 -> 192, proj NS=2 -> 128), BK=64,
// 512 threads = 8 waves (2M x 4N), per-wave 64 x NS*16.
// LDS dbuf: As[2][128*64] + Bs[2][NS*64*64] = 80 KB (NS=3) / 64 KB (NS=2)
// -> 2 blocks/CU; VGPR forced <=128 via __launch_bounds__(512,4).
//
// B-frag groups: bfA = n-subtiles [0,NA), bfC = [NA,NS); NA = NS-1.
// Per K-tile t (cur buf = t&1), 4 phases, 3 barriers:
//  ph0: issue bfC(2)+afB(4) reads [cur]; lgkm(6) drains prev-ph3's
//       afA(4)+bfA(2NA);  MFMA m01 x bfA;  BAR
//  ph1: lgkm(0) drains bfC+afB -> ALL cur-buf reads done; MFMA m01xbfC; BAR
//       (this barrier globalizes "cur buf fully read" before ph2 staging)
//  ph2: stage A(t+2)(2gl)+B(t+2)(NSgl) into CUR buf; vmcnt(2+NS) drains
//       A(t+1)+B(t+1) per-wave;  MFMA m23 x bfA;  BAR
//       (barrier globalizes vmcnt -> tile t+1 landed chip-wide)
//  ph3: read next-tile afA+bfA from OTHER buf; sched_barrier; MFMA m23xbfC
// Tail: t=14: no stage, vmcnt(0); t=15: no next reads.
// LDS swizzle (verified rounds 1-5, 0 conflicts): row-local XOR, unchanged.
// ---------------------------------------------------------------------------
template <int NS, bool SA, int VM, bool RD>
__device__ __forceinline__ void kiterN(
    f32x4 (&acc)[4][NS], bf16x8 (&afA)[2][2], bf16x8 (&bfA)[NS - 1][2],
    const u16* __restrict__ aCur, const u16* __restrict__ bCur,
    const u16* __restrict__ aNx, const u16* __restrict__ bNx,
    u16* aStg, u16* bStg, const u16* gaN, const u16* gbN, int tid,
    int aoff0, int aoff1, int boff0, int boff1) {
  constexpr int NA = NS - 1;
  bf16x8 afB[2][2], bfC[2];

  // ---- phase 0: MFMA m01 x bfA ----
  bfC[0] = *(const bf16x8*)(bCur + boff0 + NA * 1024);
  bfC[1] = *(const bf16x8*)(bCur + boff1 + NA * 1024);
#pragma unroll
  for (int m = 0; m < 2; ++m) {
    afB[m][0] = *(const bf16x8*)(aCur + aoff0 + (2 + m) * 1024);
    afB[m][1] = *(const bf16x8*)(aCur + aoff1 + (2 + m) * 1024);
  }
  wait_lgkm<6>();  // drains prev-ph3's afA+bfA (oldest), leaves the 6 above
  __builtin_amdgcn_s_setprio(1);
#pragma unroll
  for (int m = 0; m < 2; ++m)
#pragma unroll
    for (int n = 0; n < NA; ++n) {
      acc[m][n] = mfma16(afA[m][0], bfA[n][0], acc[m][n]);
      acc[m][n] = mfma16(afA[m][1], bfA[n][1], acc[m][n]);
    }
  __builtin_amdgcn_s_setprio(0);
  __builtin_amdgcn_s_barrier();

  // ---- phase 1: MFMA m01 x bfC ----
  wait_lgkm<0>();  // bfC + afB done -> all cur-buf reads complete
  __builtin_amdgcn_s_setprio(1);
#pragma unroll
  for (int m = 0; m < 2; ++m) {
    acc[m][NA] = mfma16(afA[m][0], bfC[0], acc[m][NA]);
    acc[m][NA] = mfma16(afA[m][1], bfC[1], acc[m][NA]);
  }
  __builtin_amdgcn_s_setprio(0);
  __builtin_amdgcn_s_barrier();  // globalizes cur-buf-read completion

  // ---- phase 2: stage t+2 into cur buf; MFMA m23 x bfA ----
  if (SA) {
    gload_lds16(gaN, aStg + tid * 8);
    gload_lds16(gaN + 65536, aStg + 4096 + tid * 8);
#pragma unroll
    for (int ld = 0; ld < NS; ++ld)
      gload_lds16(gbN + ld * 65536, bStg + ld * 4096 + tid * 8);
  }
  if (VM >= 0) wait_vm<(VM >= 0 ? VM : 0)>();  // t+1 landed (per wave)
  __builtin_amdgcn_s_setprio(1);
#pragma unroll
  for (int m = 0; m < 2; ++m)
#pragma unroll
    for (int n = 0; n < NA; ++n) {
      acc[2 + m][n] = mfma16(afB[m][0], bfA[n][0], acc[2 + m][n]);
      acc[2 + m][n] = mfma16(afB[m][1], bfA[n][1], acc[2 + m][n]);
    }
  __builtin_amdgcn_s_setprio(0);
  __builtin_amdgcn_s_barrier();  // globalizes vmcnt: t+1 landed chip-wide

  // ---- phase 3: read-ahead next tile; MFMA m23 x bfC ----
  if (RD) {
#pragma unroll
    for (int m = 0; m < 2; ++m) {  // afA first, then bfA (ph0 drains both)
      afA[m][0] = *(const bf16x8*)(aNx + aoff0 + m * 1024);
      afA[m][1] = *(const bf16x8*)(aNx + aoff1 + m * 1024);
    }
#pragma unroll
    for (int n = 0; n < NA; ++n) {
      bfA[n][0] = *(const bf16x8*)(bNx + boff0 + n * 1024);
      bfA[n][1] = *(const bf16x8*)(bNx + boff1 + n * 1024);
    }
    __builtin_amdgcn_sched_barrier(0);  // reads stay issued before this MFMA
  }
  __builtin_amdgcn_s_setprio(1);
#pragma unroll
  for (int m = 0; m < 2; ++m) {
    acc[2 + m][NA] = mfma16(afB[m][0], bfC[0], acc[2 + m][NA]);
    acc[2 + m][NA] = mfma16(afB[m][1], bfC[1], acc[2 + m][NA]);
  }
  __builtin_amdgcn_s_setprio(0);
}

template <int MODE>  // 0 = QKV (NS=3, routes cols to Q/K/Vt), 1 = proj (NS=2, fp32)
__global__ __launch_bounds__(512, 4) void gemm2b(
    const u16* __restrict__ A, const u16* __restrict__ Bc,
    u16* __restrict__ Qb, u16* __restrict__ Kb, u16* __restrict__ Vt,
    float* __restrict__ Cf, float qscale) {
  constexpr int NS = (MODE == 0) ? 3 : 2;   // n-subtiles per wave
  constexpr int NA = NS - 1;
  constexpr int WN = NS * 16;               // per-wave N (48 / 32)
  constexpr int K = 1024;
  __shared__ u16 As[2][8192];               // [dbuf][128 rows x 64 k]
  __shared__ u16 Bs[2][NS * 4096];          // [dbuf][NS*64 rows x 64 k]

  // XCD-bijective decode: per XCD 8 row-strips, rt-minor, then col-tiles
  const int ord = blockIdx.x;
  const int xcd = ord & 7, g = ord >> 3;
  const int rt = xcd * 8 + (g & 7);         // [0,64)
  const int ct = g >> 3;                    // MODE0: [0,16), MODE1: [0,8)
  const int colm = ct * (NS * 64);
  const int row0 = rt * 128;

  const int tid = threadIdx.x;
  const int lane = tid & 63, wid = tid >> 6;
  const int quad = lane >> 4, l15 = lane & 15;
  const int wm = wid >> 2, wn = wid & 3;

  // staging: linear LDS dest, pre-swizzled global source
  const int srow = tid >> 3;
  const int selem = ((tid & 7) ^ (srow & 7)) * 8;
  const u16* ga = A + (size_t)(row0 + srow) * K + selem;
  const u16* gb = Bc + (size_t)(colm + srow) * K + selem;

  u16* pA0 = &As[0][0];
  u16* pA1 = &As[1][0];
  u16* pB0 = &Bs[0][0];
  u16* pB1 = &Bs[1][0];

  // swizzled fragment read offsets (elements); row-local swizzle unchanged
  const int swz = 8 * (quad ^ (l15 & 3));
  const int kof = 32 * ((l15 >> 2) & 1);
  const int aoff0 = (wm * 64 + l15) * 64 + swz + kof;
  const int aoff1 = (wm * 64 + l15) * 64 + swz + (32 - kof);
  const int boff0 = (wn * WN + l15) * 64 + swz + kof;
  const int boff1 = (wn * WN + l15) * 64 + swz + (32 - kof);

  f32x4 acc[4][NS];
  const f32x4 zero = {0.f, 0.f, 0.f, 0.f};
#pragma unroll
  for (int m = 0; m < 4; ++m)
#pragma unroll
    for (int n = 0; n < NS; ++n) acc[m][n] = zero;

  bf16x8 afA[2][2], bfA[NA][2];

  // prologue: stage A(0),B(0),A(1),B(1); vmcnt(2+NS) leaves t1 in flight;
  // then pre-issue tile-0 ph0 fragments (afA, bfA) -- plays prev-ph3's role
  gload_lds16(ga, pA0 + tid * 8);
  gload_lds16(ga + 65536, pA0 + 4096 + tid * 8);
#pragma unroll
  for (int ld = 0; ld < NS; ++ld)
    gload_lds16(gb + ld * 65536, pB0 + ld * 4096 + tid * 8);
  gload_lds16(ga + 64, pA1 + tid * 8);
  gload_lds16(ga + 64 + 65536, pA1 + 4096 + tid * 8);
#pragma unroll
  for (int ld = 0; ld < NS; ++ld)
    gload_lds16(gb + 64 + ld * 65536, pB1 + ld * 4096 + tid * 8);
  wait_vm<2 + NS>();
  __builtin_amdgcn_s_barrier();
#pragma unroll
  for (int m = 0; m < 2; ++m) {
    afA[m][0] = *(const bf16x8*)(pA0 + aoff0 + m * 1024);
    afA[m][1] = *(const bf16x8*)(pA0 + aoff1 + m * 1024);
  }
#pragma unroll
  for (int n = 0; n < NA; ++n) {
    bfA[n][0] = *(const bf16x8*)(pB0 + boff0 + n * 1024);
    bfA[n][1] = *(const bf16x8*)(pB0 + boff1 + n * 1024);
  }

  // main loop: t=0..13 (7 pairs); tail t=14 (no stage, vmcnt 0), t=15
#pragma unroll 1
  for (int tp = 0; tp < 7; ++tp) {
    const int kb = tp * 128;
    kiterN<NS, true, 2 + NS, true>(acc, afA, bfA, pA0, pB0, pA1, pB1,
                                   pA0, pB0, ga + kb + 128, gb + kb + 128,
                                   tid, aoff0, aoff1, boff0, boff1);
    kiterN<NS, true, 2 + NS, true>(acc, afA, bfA, pA1, pB1, pA0, pB0,
                                   pA1, pB1, ga + kb + 192, gb + kb + 192,
                                   tid, aoff0, aoff1, boff0, boff1);
  }
  kiterN<NS, false, 0, true>(acc, afA, bfA, pA0, pB0, pA1, pB1,
                             pA0, pB0, ga, gb,
                             tid, aoff0, aoff1, boff0, boff1);
  kiterN<NS, false, -1, false>(acc, afA, bfA, pA1, pB1, pA0, pB0,
                               pA1, pB1, ga, gb,
                               tid, aoff0, aoff1, boff0, boff1);

  // ---- epilogue ----
  if (MODE == 1) {
#pragma unroll
    for (int m = 0; m < 4; ++m) {
      const int rg = row0 + wm * 64 + m * 16 + quad * 4;
#pragma unroll
      for (int n = 0; n < NS; ++n) {
        const int cg = colm + wn * WN + n * 16 + l15;
#pragma unroll
        for (int r = 0; r < 4; ++r)
          Cf[(size_t)(rg + r) * 1024 + cg] = acc[m][n][r];
      }
    }
    return;
  }
  // MODE 0: route each 16-col subtile to Q (scaled), K, or Vt (transposed)
#pragma unroll
  for (int m = 0; m < 4; ++m) {
    const int rg = row0 + wm * 64 + m * 16 + quad * 4;  // token row, r=0
    const int bb = rg >> 11, t = rg & 2047;
#pragma unroll
    for (int n = 0; n < NS; ++n) {
      const int cg0 = colm + wn * WN + n * 16;  // 16-aligned, never spans z
      const int z = cg0 >> 10;
      const int c1 = (cg0 & 1023) + l15;
      if (z == 2) {
        // V -> Vt[(b*16+h)*64+d][t], 8B t-contiguous vector store
        ushort4 w;
        w.x = f32_bf16(acc[m][n][0]);
        w.y = f32_bf16(acc[m][n][1]);
        w.z = f32_bf16(acc[m][n][2]);
        w.w = f32_bf16(acc[m][n][3]);
        *(ushort4*)(Vt + ((size_t)(bb * 16 + (c1 >> 6)) * 64 + (c1 & 63)) * 2048 + t) = w;
      } else {
        u16* C = z ? Kb : Qb;
        const float sc = z ? 1.0f : qscale;
#pragma unroll
        for (int r = 0; r < 4; ++r)
          C[(size_t)(rg + r) * 1024 + c1] = f32_bf16(acc[m][n][r] * sc);
      }
    }
  }
}

// ---------------------------------------------------------------------------
// Flash attention, causal, KEY-SPLIT blocks (unchanged from round 5).
// 512 threads = 8 waves: waves 0-3 keys [0,n/2), waves 4-7 keys [n/2,n).
// Max-free softmax -> partials additive; in-LDS merge. Longest-first grid.
// ---------------------------------------------------------------------------
__global__ __launch_bounds__(512, 4) void attn_kernel(
    const u16* __restrict__ Qb, const u16* __restrict__ Kb,
    const u16* __restrict__ Vt, u16* __restrict__ Ob, int T) {
  // carve: Ks[2 str][3][2048] | Vs[2 str][3][2048] | Ps[8][1280]  (u16 units)
  __shared__ __align__(16) u16 smem[12288 * 2 + 8 * 1280];

  const int ord = blockIdx.x;
  const int qblk = 15 - (ord >> 6);   // longest first
  const int bh = ord & 63;
  const int b = bh >> 4, h = bh & 15;
  const int tid = threadIdx.x, lane = tid & 63, wid = tid >> 6;  // 0..7
  const int qwave = wid & 3, half = wid >> 2;
  const int quad = lane >> 4, l15 = lane & 15;
  const int qb0 = qblk * 128;
  const int D = 1024;
  const int sw = l15 & 7;          // K-row swizzle key
  const int swv = (l15 >> 1) & 3;  // V-row swizzle key

  const int n = 4 * (qblk + 1);    // total key tiles for this q-tile
  const int nt2 = n >> 1;          // per-stream tiles (>= 2)
  const int tb0 = half * nt2;      // global tile offset of this stream

  u16* KsB = smem + half * 6144;
  u16* VsB = smem + 12288 + half * 6144;
  u16* PsW = smem + 24576 + wid * 1280;

  // Q fragments (B-operand: n=l15 -> q, k=quad*8+j -> feat), 2 q-subtiles
  bf16x8 qf[2][2];
#pragma unroll
  for (int qs = 0; qs < 2; ++qs) {
    const int q = qb0 + qwave * 32 + qs * 16 + l15;
    const u16* qp = Qb + ((size_t)b * T + q) * D + h * 64 + quad * 8;
    qf[qs][0] = *(const bf16x8*)(qp);
    qf[qs][1] = *(const bf16x8*)(qp + 32);
  }

  const f32x4 zero = {0.f, 0.f, 0.f, 0.f};
  f32x4 o[2][4];  // [q-subtile][d-subtile]
#pragma unroll
  for (int ms = 0; ms < 2; ++ms)
    for (int nt = 0; nt < 4; ++nt) o[ms][nt] = zero;
  float l_acc[2] = {0.f, 0.f};

  bf16x8 vf_h[4];
  bf16x8 pf_h[2];

  // staging source addresses (group-local tid, per-stream key base)
  const int t256 = tid & 255;
  const int krow = t256 >> 3, kslot = t256 & 7;
  const u16* kg = Kb + ((size_t)b * T + tb0 * 32 + krow) * D + h * 64 +
                  (kslot ^ (krow & 7)) * 8;
  const int vrow = t256 >> 2, vslot = t256 & 3;
  const u16* vg = Vt + ((size_t)bh * 64 + vrow) * T + tb0 * 32 +
                  (vslot ^ ((vrow >> 1) & 3)) * 8;

  // prefetch tiles 0 and 1 of this stream
  gload_lds16(kg, KsB + t256 * 8);
  gload_lds16(vg, VsB + t256 * 8);
  gload_lds16(kg + (size_t)32 * D, KsB + 2048 + t256 * 8);
  gload_lds16(vg + 32, VsB + 2048 + t256 * 8);
  barrier_vm2();  // tile-0 data landed; tile-1 loads may stay in flight

  int c = 0;  // ring index t % 3
  for (int t = 0; t < nt2; ++t) {
    // prefetch tile t+2 (clamped dummy at the tail keeps vmcnt uniform)
    {
      int pb = c + 2; if (pb >= 3) pb -= 3;
      const int tp = (t + 2 < nt2) ? t + 2 : nt2 - 1;
      const size_t kv = (size_t)tp * 32;
      gload_lds16(kg + kv * D, KsB + pb * 2048 + t256 * 8);
      gload_lds16(vg + kv, VsB + pb * 2048 + t256 * 8);
    }
    const u16* KsC = KsB + c * 2048;
    const u16* VsC = VsB + c * 2048;
    const int gt = tb0 + t;          // global key-tile index
    const int kv0 = gt * 32;

    // --- QK(t): S^T[key][q], A = K rows (2 subtiles), B = Q (2 subtiles)
    f32x4 s[2][2];
#pragma unroll
    for (int st = 0; st < 2; ++st) {
      const int row = st * 16 + l15;
      const bf16x8 k0 = *(const bf16x8*)(&KsC[row * 64 + ((quad ^ sw) * 8)]);
      const bf16x8 k1 = *(const bf16x8*)(&KsC[row * 64 + (((4 + quad) ^ sw) * 8)]);
#pragma unroll
      for (int qs = 0; qs < 2; ++qs) {
        s[st][qs] = mfma16(k0, qf[qs][0], zero);
        s[st][qs] = mfma16(k1, qf[qs][1], s[st][qs]);
      }
    }

    // --- PV(t-1): independent of s(t); overlaps QK in the MFMA pipe
    if (t > 0) {
#pragma unroll
      for (int nt = 0; nt < 4; ++nt)
#pragma unroll
        for (int ms = 0; ms < 2; ++ms)
          o[ms][nt] = mfma16(pf_h[ms], vf_h[nt], o[ms][nt]);
    }

    // --- V(t) fragments into registers (independent of s)
#pragma unroll
    for (int nt = 0; nt < 4; ++nt)
      vf_h[nt] = *(const bf16x8*)(
          &VsC[(nt * 16 + l15) * 32 + ((quad ^ swv) * 8)]);

    // --- causal mask: global tile gt >= n-4 straddles the q-range
    if (gt >= n - 4) {
#pragma unroll
      for (int qs = 0; qs < 2; ++qs) {
        const int q = qb0 + qwave * 32 + qs * 16 + l15;
#pragma unroll
        for (int st = 0; st < 2; ++st)
#pragma unroll
          for (int r = 0; r < 4; ++r) {
            const int key = kv0 + st * 16 + quad * 4 + r;
            if (key > q) s[st][qs][r] = -INFINITY;
          }
      }
    }

    // --- max-free softmax: p = 2^s (Q pre-scaled by log2e); l per-lane
#pragma unroll
    for (int qs = 0; qs < 2; ++qs) {
      float sum = l_acc[qs];
#pragma unroll
      for (int st = 0; st < 2; ++st)
#pragma unroll
        for (int r = 0; r < 4; ++r) {
          const float p = __builtin_amdgcn_exp2f(s[st][qs][r]);
          s[st][qs][r] = p;
          sum += p;
        }
      l_acc[qs] = sum;
    }

    // --- P^T -> LDS (A-layout for PV), 8B vector stores, stride 40
#pragma unroll
    for (int qs = 0; qs < 2; ++qs)
#pragma unroll
      for (int st = 0; st < 2; ++st) {
        bf16x4 w;
        w[0] = (__bf16)s[st][qs][0];
        w[1] = (__bf16)s[st][qs][1];
        w[2] = (__bf16)s[st][qs][2];
        w[3] = (__bf16)s[st][qs][3];
        *(bf16x4*)(&PsW[(qs * 16 + l15) * 40 + st * 16 + quad * 4]) = w;
      }

    // --- P(t) fragments for next iteration's PV (same-wave DS is in-order)
#pragma unroll
    for (int ms = 0; ms < 2; ++ms)
      pf_h[ms] = *(const bf16x8*)(&PsW[(ms * 16 + l15) * 40 + quad * 8]);

    barrier_vm2();  // t+1 data landed; t+2 loads stay in flight
    ++c; if (c >= 3) c = 0;
  }

  // --- flush PV(last)
#pragma unroll
  for (int nt = 0; nt < 4; ++nt)
#pragma unroll
    for (int ms = 0; ms < 2; ++ms)
      o[ms][nt] = mfma16(pf_h[ms], vf_h[nt], o[ms][nt]);

  // --- merge halves via LDS (overlaid on K/V rings; drain async loads 1st)
  wait_vm<0>();
  __syncthreads();
  float* mo = (float*)smem;            // [4][64][32] f32 (32 KB)
  float* ml = (float*)smem + 8192;     // [4][64][2]  f32 (2 KB)
  if (half == 1) {
    float* dst = mo + (qwave * 64 + lane) * 32;
#pragma unroll
    for (int ms = 0; ms < 2; ++ms)
#pragma unroll
      for (int nt = 0; nt < 4; ++nt)
#pragma unroll
        for (int r = 0; r < 4; ++r)
          dst[ms * 16 + nt * 4 + r] = o[ms][nt][r];
    ml[(qwave * 64 + lane) * 2 + 0] = l_acc[0];
    ml[(qwave * 64 + lane) * 2 + 1] = l_acc[1];
  }
  __syncthreads();
  if (half == 1) return;
  {
    const float* src = mo + (qwave * 64 + lane) * 32;
#pragma unroll
    for (int ms = 0; ms < 2; ++ms)
#pragma unroll
      for (int nt = 0; nt < 4; ++nt)
#pragma unroll
        for (int r = 0; r < 4; ++r)
          o[ms][nt][r] += src[ms * 16 + nt * 4 + r];
    l_acc[0] += ml[(qwave * 64 + lane) * 2 + 0];
    l_acc[1] += ml[(qwave * 64 + lane) * 2 + 1];
  }

  // epilogue: reduce l across the 4 quads (once), normalize, store
#pragma unroll
  for (int ms = 0; ms < 2; ++ms) {
    float sum = l_acc[ms];
    sum += __shfl_xor(sum, 16);
    sum += __shfl_xor(sum, 32);
    const float linv = 1.0f / sum;
    float lr[4];
#pragma unroll
    for (int r = 0; r < 4; ++r) lr[r] = __shfl(linv, quad * 4 + r);
#pragma unroll
    for (int r = 0; r < 4; ++r) {
      const int qo = qb0 + qwave * 32 + ms * 16 + quad * 4 + r;
      u16* op = Ob + ((size_t)b * T + qo) * D + h * 64 + l15;
#pragma unroll
      for (int nt = 0; nt < 4; ++nt)
        op[nt * 16] = f32_bf16(o[ms][nt][r] * lr[r]);
    }
  }
}

// ---------------------------------------------------------------------------
extern "C" void kernel_launch(void* const* d_in, const int* in_sizes, int n_in,
                              void* d_out, int out_size, void* d_ws, size_t ws_size,
                              hipStream_t stream) {
  const float* x  = (const float*)d_in[0];
  const float* wq = (const float*)d_in[1];
  const float* wk = (const float*)d_in[2];
  const float* wv = (const float*)d_in[3];
  const float* wo = (const float*)d_in[4];

  const int B = 4, T = 2048, D = 1024;
  const int M = B * T;  // 8192

  u16* ws = (u16*)d_ws;
  u16* xb  = ws;                         // M*D
  u16* wqb = xb  + (size_t)M * D;        // D*D (contiguous with xb: fused cast;
  u16* wkb = wqb + (size_t)D * D;        //  wq/wk/wv contiguous -> one 3072x1024 B)
  u16* wvb = wkb + (size_t)D * D;
  u16* wob = wvb + (size_t)D * D;
  u16* Qb  = wob + (size_t)D * D;        // M*D (pre-scaled by log2e/8)
  u16* Kb  = Qb  + (size_t)M * D;
  u16* Vt  = Kb  + (size_t)M * D;        // transposed V: [bh][d][t] (from GEMM)
  u16* Ob  = Vt  + (size_t)M * D;        // attention output

  (void)wkb; (void)wvb;

  // fused cast (dst regions xb..wob are contiguous)
  const int n_x = M * D / 4, n_w = D * D / 4;
  const int n_tot = n_x + 4 * n_w;
  cvt_all_kernel<<<(n_tot + 255) / 256, 256, 0, stream>>>(x, wq, wk, wv, wo,
                                                          xb, n_x, n_w);

  // fused QKV projection: 64 row-tiles x 16 col-tiles (128x192) = 1024
  // blocks, 2 blocks/CU; Q scaled by (1/sqrt(Dh)) * log2(e)
  gemm2b<0><<<1024, 512, 0, stream>>>(
      xb, wqb, Qb, Kb, Vt, nullptr, 0.125f * 1.44269504f);

  // flash attention: 16 q-tiles x 64 bh = 1024 blocks of 512 threads,
  // key-split halves in-block, longest blocks dispatched first
  attn_kernel<<<dim3(1024), 512, 0, stream>>>(Qb, Kb, Vt, Ob, T);

  // output projection -> fp32 d_out: 64 x 8 (128x128) = 512 blocks,
  // 2 blocks/CU -> fully resident in one generation
  gemm2b<1><<<512, 512, 0, stream>>>(
      Ob, wob, nullptr, nullptr, nullptr, (float*)d_out, 1.0f);
}

// Round 7
// 224.177 us; speedup vs baseline: 1.1008x; 1.1008x over previous
//
#include <hip/hip_runtime.h>
#include <cstdint>
#include <math.h>

// ---------------------------------------------------------------------------
// CausalSelfAttention (B=4, T=2048, D=1024, H=16, Dh=64), fp32 in/out,
// bf16 MFMA compute internally.
// Pipeline: fused cast -> fused QKV GEMM (128x384, read-ahead counted-lgkm,
//           round-4 proven config) -> flash attention (key-split round 5
//           + setprio on MFMA clusters) -> output projection (128x256,
//           round-4 proven config).
//
// Round-7 rationale: round 6 (128x192, 2 blk/CU) regressed QKV 66->87us:
// the GEMM is LDS-read-bound (reads:MFMA ~ 4:1), so doubling per-CU LDS
// demand with a worse reads-per-FLOP tile hurt. Revert GEMMs to the proven
// round-4 geometry; attn gets T5 setprio (2 independent blocks/CU = the
// regime where it pays; null-risk only).
// ---------------------------------------------------------------------------

typedef unsigned short u16;
typedef __bf16 bf16x8 __attribute__((ext_vector_type(8)));
typedef __bf16 bf16x4 __attribute__((ext_vector_type(4)));
typedef float f32x4 __attribute__((ext_vector_type(4)));

__device__ __forceinline__ u16 f32_bf16(float f) {  // round-nearest-even
  union { float f; uint32_t u; } c; c.f = f;
  uint32_t u = c.u;
  return (u16)((u + 0x7FFFu + ((u >> 16) & 1u)) >> 16);
}

__device__ __forceinline__ f32x4 mfma16(bf16x8 a, bf16x8 b, f32x4 c) {
  return __builtin_amdgcn_mfma_f32_16x16x32_bf16(a, b, c, 0, 0, 0);
}

// async global->LDS, 16B/lane. LDS dest must be wave-uniform base + lane*16.
__device__ __forceinline__ void gload_lds16(const u16* g, u16* l) {
  __builtin_amdgcn_global_load_lds(
      (const __attribute__((address_space(1))) void*)g,
      (__attribute__((address_space(3))) void*)l, 16, 0, 0);
}

template <int N>
__device__ __forceinline__ void wait_lgkm() {
  if (N == 0)       asm volatile("s_waitcnt lgkmcnt(0)" ::: "memory");
  else if (N == 4)  asm volatile("s_waitcnt lgkmcnt(4)" ::: "memory");
  else if (N == 8)  asm volatile("s_waitcnt lgkmcnt(8)" ::: "memory");
  else if (N == 10) asm volatile("s_waitcnt lgkmcnt(10)" ::: "memory");
  __builtin_amdgcn_sched_barrier(0);
}
template <int N>
__device__ __forceinline__ void wait_vm() {
  if (N == 6)      asm volatile("s_waitcnt vmcnt(6)" ::: "memory");
  else if (N == 4) asm volatile("s_waitcnt vmcnt(4)" ::: "memory");
  else if (N == 2) asm volatile("s_waitcnt vmcnt(2)" ::: "memory");
  else if (N == 0) asm volatile("s_waitcnt vmcnt(0)" ::: "memory");
  __builtin_amdgcn_sched_barrier(0);
}

// barrier that does NOT drain the newest 2 vm loads (attn t+2 prefetch)
__device__ __forceinline__ void barrier_vm2() {
  asm volatile("s_waitcnt vmcnt(2)" ::: "memory");
  __builtin_amdgcn_sched_barrier(0);
  __builtin_amdgcn_s_barrier();
}

// ---------------------------------------------------------------------------
// fused cast fp32->bf16 of x + 4 weights into contiguous ws region
// ---------------------------------------------------------------------------
__global__ __launch_bounds__(256) void cvt_all_kernel(
    const float* __restrict__ x,
    const float* __restrict__ wq, const float* __restrict__ wk,
    const float* __restrict__ wv, const float* __restrict__ wo,
    u16* __restrict__ dst, int n_x, int n_w) {
  int i = blockIdx.x * 256 + threadIdx.x;
  const float* src;
  int off;
  if (i < n_x) { src = x; off = i; }
  else {
    int j = i - n_x;
    int w = j / n_w;  off = j - w * n_w;
    src = (w == 0) ? wq : (w == 1) ? wk : (w == 2) ? wv : wo;
  }
  float4 f = ((const float4*)src)[off];
  ushort4 o;
  o.x = f32_bf16(f.x); o.y = f32_bf16(f.y);
  o.z = f32_bf16(f.z); o.w = f32_bf16(f.w);
  ((ushort4*)dst)[i] = o;
}

// ---------------------------------------------------------------------------
// Read-ahead GEMM (round-4 proven): C[m,n] = sum_k A[m,k]*B[n,k].
// BM=128, BN=NS*64 (QKV: NS=6 -> 384, proj: NS=4 -> 256), BK=64,
// 512 threads = 8 waves (2M x 4N), per-wave 64 x NS*16.
// Per-phase: issue NEXT phase's ds_reads, counted lgkmcnt for the previous
// phase's -> LDS service hides under MFMA clusters. Counted vmcnt(NS),
// never 0 in the main loop. LDS swizzle: 0 bank conflicts (verified).
// ---------------------------------------------------------------------------
template <int NS, bool SA, bool SB, int VM, bool RD>
__device__ __forceinline__ void kiter(
    f32x4 (&acc)[4][NS], bf16x8 (&afA)[2][2], bf16x8 (&bfAr)[NS / 2][2],
    const u16* __restrict__ aCur, const u16* __restrict__ bCur,
    const u16* __restrict__ aNx, const u16* __restrict__ bNx,
    u16* aStg, u16* bStg,
    const u16* gaN, const u16* gbN2, int tid,
    int aoff0, int aoff1, int boff0, int boff1) {
  constexpr int NB = NS / 2;
  bf16x8 afB[2][2], bfB[NB][2];

  // ---- phase 0 ----
#pragma unroll
  for (int n = 0; n < NB; ++n) {  // bfB first (ph1 waits on it)
    bfB[n][0] = *(const bf16x8*)(bCur + boff0 + (NB + n) * 1024);
    bfB[n][1] = *(const bf16x8*)(bCur + boff1 + (NB + n) * 1024);
  }
#pragma unroll
  for (int m = 0; m < 2; ++m) {
    afB[m][0] = *(const bf16x8*)(aCur + aoff0 + (2 + m) * 1024);
    afB[m][1] = *(const bf16x8*)(aCur + aoff1 + (2 + m) * 1024);
  }
  if (SA) {
    gload_lds16(gaN, aStg + tid * 8);
    gload_lds16(gaN + 65536, aStg + 4096 + tid * 8);
  }
  wait_lgkm<2 * NB + 4>();
  __builtin_amdgcn_s_setprio(1);
#pragma unroll
  for (int m = 0; m < 2; ++m)
#pragma unroll
    for (int n = 0; n < NB; ++n) {
      acc[m][n] = mfma16(afA[m][0], bfAr[n][0], acc[m][n]);
      acc[m][n] = mfma16(afA[m][1], bfAr[n][1], acc[m][n]);
    }
  __builtin_amdgcn_s_setprio(0);
  __builtin_amdgcn_s_barrier();

  // ---- phase 1 ----
  wait_lgkm<4>();
  __builtin_amdgcn_s_setprio(1);
#pragma unroll
  for (int m = 0; m < 2; ++m)
#pragma unroll
    for (int n = 0; n < NB; ++n) {
      acc[m][NB + n] = mfma16(afA[m][0], bfB[n][0], acc[m][NB + n]);
      acc[m][NB + n] = mfma16(afA[m][1], bfB[n][1], acc[m][NB + n]);
    }
  __builtin_amdgcn_s_setprio(0);
  __builtin_amdgcn_s_barrier();

  // ---- phase 2 ----
  if (SB) {
#pragma unroll
    for (int ld = 0; ld < NS; ++ld)
      gload_lds16(gbN2 + ld * 65536, bStg + ld * 4096 + tid * 8);
  }
  if (VM >= 0) wait_vm<(VM >= 0 ? VM : 0)>();
  wait_lgkm<0>();
  __builtin_amdgcn_s_setprio(1);
#pragma unroll
  for (int m = 0; m < 2; ++m)
#pragma unroll
    for (int n = 0; n < NB; ++n) {
      acc[2 + m][n] = mfma16(afB[m][0], bfAr[n][0], acc[2 + m][n]);
      acc[2 + m][n] = mfma16(afB[m][1], bfAr[n][1], acc[2 + m][n]);
    }
  __builtin_amdgcn_s_setprio(0);
  __builtin_amdgcn_s_barrier();

  // ---- phase 3 ----
  if (RD) {
#pragma unroll
    for (int m = 0; m < 2; ++m) {  // afA first, then bfA (ph0 drains both)
      afA[m][0] = *(const bf16x8*)(aNx + aoff0 + m * 1024);
      afA[m][1] = *(const bf16x8*)(aNx + aoff1 + m * 1024);
    }
#pragma unroll
    for (int n = 0; n < NB; ++n) {
      bfAr[n][0] = *(const bf16x8*)(bNx + boff0 + n * 1024);
      bfAr[n][1] = *(const bf16x8*)(bNx + boff1 + n * 1024);
    }
    __builtin_amdgcn_sched_barrier(0);  // reads issued before this MFMA
  }
  __builtin_amdgcn_s_setprio(1);
#pragma unroll
  for (int m = 0; m < 2; ++m)
#pragma unroll
    for (int n = 0; n < NB; ++n) {
      acc[2 + m][NB + n] = mfma16(afB[m][0], bfB[n][0], acc[2 + m][NB + n]);
      acc[2 + m][NB + n] = mfma16(afB[m][1], bfB[n][1], acc[2 + m][NB + n]);
    }
  __builtin_amdgcn_s_setprio(0);
  __builtin_amdgcn_s_barrier();
}

template <int MODE>  // 0 = QKV (NS=6, routes cols to Q/K/Vt), 1 = proj (NS=4, fp32)
__global__ __launch_bounds__(512, 2) void gemm8p(
    const u16* __restrict__ A, const u16* __restrict__ Bc,
    u16* __restrict__ Qb, u16* __restrict__ Kb, u16* __restrict__ Vt,
    float* __restrict__ Cf, float qscale) {
  constexpr int NS = (MODE == 0) ? 6 : 4;   // n-subtiles per wave
  constexpr int NB = NS / 2;
  constexpr int WN = NS * 16;               // per-wave N (96 / 64)
  constexpr int K = 1024;
  __shared__ u16 As[2][8192];               // [dbuf][128 rows x 64 k]
  __shared__ u16 Bs[2][NS * 4096];          // [dbuf][NS*64 rows x 64 k]

  // XCD-bijective decode: per XCD 8 row-strips x (8 or 4) col-tiles
  const int ord = blockIdx.x;
  const int xcd = ord & 7, g = ord >> 3;
  const int rt = xcd * 8 + (g & 7);         // [0,64)
  const int ct = g >> 3;                    // MODE0: [0,8), MODE1: [0,4)
  const int colm = ct * (NS * 64);
  const int row0 = rt * 128;

  const int tid = threadIdx.x;
  const int lane = tid & 63, wid = tid >> 6;
  const int quad = lane >> 4, l15 = lane & 15;
  const int wm = wid >> 2, wn = wid & 3;

  // staging: linear LDS dest, pre-swizzled global source
  const int srow = tid >> 3;
  const int selem = ((tid & 7) ^ (srow & 7)) * 8;
  const u16* ga = A + (size_t)(row0 + srow) * K + selem;
  const u16* gb = Bc + (size_t)(colm + srow) * K + selem;

  u16* pA0 = &As[0][0];
  u16* pA1 = &As[1][0];
  u16* pB0 = &Bs[0][0];
  u16* pB1 = &Bs[1][0];

  // swizzled fragment read offsets (elements); row-local swizzle unchanged
  const int swz = 8 * (quad ^ (l15 & 3));
  const int kof = 32 * ((l15 >> 2) & 1);
  const int aoff0 = (wm * 64 + l15) * 64 + swz + kof;
  const int aoff1 = (wm * 64 + l15) * 64 + swz + (32 - kof);
  const int boff0 = (wn * WN + l15) * 64 + swz + kof;
  const int boff1 = (wn * WN + l15) * 64 + swz + (32 - kof);

  f32x4 acc[4][NS];
  const f32x4 zero = {0.f, 0.f, 0.f, 0.f};
#pragma unroll
  for (int m = 0; m < 4; ++m)
#pragma unroll
    for (int n = 0; n < NS; ++n) acc[m][n] = zero;

  bf16x8 afA[2][2], bfAr[NB][2];

  // prologue: stage A(0), B(0), B(1); vmcnt(NS) leaves B(1) in flight;
  // then pre-issue tile-0 ph0 fragments (afA, bfA)
  gload_lds16(ga, pA0 + tid * 8);
  gload_lds16(ga + 65536, pA0 + 4096 + tid * 8);
#pragma unroll
  for (int ld = 0; ld < NS; ++ld)
    gload_lds16(gb + ld * 65536, pB0 + ld * 4096 + tid * 8);
#pragma unroll
  for (int ld = 0; ld < NS; ++ld)
    gload_lds16(gb + 64 + ld * 65536, pB1 + ld * 4096 + tid * 8);
  wait_vm<NS>();
  __builtin_amdgcn_s_barrier();
#pragma unroll
  for (int m = 0; m < 2; ++m) {
    afA[m][0] = *(const bf16x8*)(pA0 + aoff0 + m * 1024);
    afA[m][1] = *(const bf16x8*)(pA0 + aoff1 + m * 1024);
  }
#pragma unroll
  for (int n = 0; n < NB; ++n) {
    bfAr[n][0] = *(const bf16x8*)(pB0 + boff0 + n * 1024);
    bfAr[n][1] = *(const bf16x8*)(pB0 + boff1 + n * 1024);
  }

  // main loop: t=0..13 (7 pairs); tail t=14 (stage A(15), vmcnt 0), t=15
#pragma unroll 1
  for (int tp = 0; tp < 7; ++tp) {
    const int kb = tp * 128;
    kiter<NS, true, true, NS, true>(acc, afA, bfAr, pA0, pB0, pA1, pB1,
                                    pA1, pB0, ga + kb + 64, gb + kb + 128,
                                    tid, aoff0, aoff1, boff0, boff1);
    kiter<NS, true, true, NS, true>(acc, afA, bfAr, pA1, pB1, pA0, pB0,
                                    pA0, pB1, ga + kb + 128, gb + kb + 192,
                                    tid, aoff0, aoff1, boff0, boff1);
  }
  kiter<NS, true, false, 0, true>(acc, afA, bfAr, pA0, pB0, pA1, pB1,
                                  pA1, pB0, ga + 960, gb,
                                  tid, aoff0, aoff1, boff0, boff1);
  kiter<NS, false, false, -1, false>(acc, afA, bfAr, pA1, pB1, pA0, pB0,
                                     pA0, pB1, ga, gb,
                                     tid, aoff0, aoff1, boff0, boff1);

  // ---- epilogue ----
  if (MODE == 1) {
#pragma unroll
    for (int m = 0; m < 4; ++m) {
      const int rg = row0 + wm * 64 + m * 16 + quad * 4;
#pragma unroll
      for (int n = 0; n < NS; ++n) {
        const int cg = colm + wn * WN + n * 16 + l15;
#pragma unroll
        for (int r = 0; r < 4; ++r)
          Cf[(size_t)(rg + r) * 1024 + cg] = acc[m][n][r];
      }
    }
    return;
  }
  // MODE 0: route each 16-col subtile to Q (scaled), K, or Vt (transposed)
#pragma unroll
  for (int m = 0; m < 4; ++m) {
    const int rg = row0 + wm * 64 + m * 16 + quad * 4;  // token row, r=0
    const int bb = rg >> 11, t = rg & 2047;
#pragma unroll
    for (int n = 0; n < NS; ++n) {
      const int cg0 = colm + wn * WN + n * 16;  // 16-aligned, never spans z
      const int z = cg0 >> 10;
      const int c1 = (cg0 & 1023) + l15;
      if (z == 2) {
        // V -> Vt[(b*16+h)*64+d][t], 8B t-contiguous vector store
        ushort4 w;
        w.x = f32_bf16(acc[m][n][0]);
        w.y = f32_bf16(acc[m][n][1]);
        w.z = f32_bf16(acc[m][n][2]);
        w.w = f32_bf16(acc[m][n][3]);
        *(ushort4*)(Vt + ((size_t)(bb * 16 + (c1 >> 6)) * 64 + (c1 & 63)) * 2048 + t) = w;
      } else {
        u16* C = z ? Kb : Qb;
        const float sc = z ? 1.0f : qscale;
#pragma unroll
        for (int r = 0; r < 4; ++r)
          C[(size_t)(rg + r) * 1024 + c1] = f32_bf16(acc[m][n][r] * sc);
      }
    }
  }
}

// ---------------------------------------------------------------------------
// Flash attention, causal, KEY-SPLIT blocks (round 5) + setprio on MFMA.
// 512 threads = 8 waves: waves 0-3 keys [0,n/2), waves 4-7 keys [n/2,n).
// Max-free softmax -> partials additive; in-LDS merge. Longest-first grid.
// ---------------------------------------------------------------------------
__global__ __launch_bounds__(512, 4) void attn_kernel(
    const u16* __restrict__ Qb, const u16* __restrict__ Kb,
    const u16* __restrict__ Vt, u16* __restrict__ Ob, int T) {
  // carve: Ks[2 str][3][2048] | Vs[2 str][3][2048] | Ps[8][1280]  (u16 units)
  __shared__ __align__(16) u16 smem[12288 * 2 + 8 * 1280];

  const int ord = blockIdx.x;
  const int qblk = 15 - (ord >> 6);   // longest first
  const int bh = ord & 63;
  const int b = bh >> 4, h = bh & 15;
  const int tid = threadIdx.x, lane = tid & 63, wid = tid >> 6;  // 0..7
  const int qwave = wid & 3, half = wid >> 2;
  const int quad = lane >> 4, l15 = lane & 15;
  const int qb0 = qblk * 128;
  const int D = 1024;
  const int sw = l15 & 7;          // K-row swizzle key
  const int swv = (l15 >> 1) & 3;  // V-row swizzle key

  const int n = 4 * (qblk + 1);    // total key tiles for this q-tile
  const int nt2 = n >> 1;          // per-stream tiles (>= 2)
  const int tb0 = half * nt2;      // global tile offset of this stream

  u16* KsB = smem + half * 6144;
  u16* VsB = smem + 12288 + half * 6144;
  u16* PsW = smem + 24576 + wid * 1280;

  // Q fragments (B-operand: n=l15 -> q, k=quad*8+j -> feat), 2 q-subtiles
  bf16x8 qf[2][2];
#pragma unroll
  for (int qs = 0; qs < 2; ++qs) {
    const int q = qb0 + qwave * 32 + qs * 16 + l15;
    const u16* qp = Qb + ((size_t)b * T + q) * D + h * 64 + quad * 8;
    qf[qs][0] = *(const bf16x8*)(qp);
    qf[qs][1] = *(const bf16x8*)(qp + 32);
  }

  const f32x4 zero = {0.f, 0.f, 0.f, 0.f};
  f32x4 o[2][4];  // [q-subtile][d-subtile]
#pragma unroll
  for (int ms = 0; ms < 2; ++ms)
    for (int nt = 0; nt < 4; ++nt) o[ms][nt] = zero;
  float l_acc[2] = {0.f, 0.f};

  bf16x8 vf_h[4];
  bf16x8 pf_h[2];

  // staging source addresses (group-local tid, per-stream key base)
  const int t256 = tid & 255;
  const int krow = t256 >> 3, kslot = t256 & 7;
  const u16* kg = Kb + ((size_t)b * T + tb0 * 32 + krow) * D + h * 64 +
                  (kslot ^ (krow & 7)) * 8;
  const int vrow = t256 >> 2, vslot = t256 & 3;
  const u16* vg = Vt + ((size_t)bh * 64 + vrow) * T + tb0 * 32 +
                  (vslot ^ ((vrow >> 1) & 3)) * 8;

  // prefetch tiles 0 and 1 of this stream
  gload_lds16(kg, KsB + t256 * 8);
  gload_lds16(vg, VsB + t256 * 8);
  gload_lds16(kg + (size_t)32 * D, KsB + 2048 + t256 * 8);
  gload_lds16(vg + 32, VsB + 2048 + t256 * 8);
  barrier_vm2();  // tile-0 data landed; tile-1 loads may stay in flight

  int c = 0;  // ring index t % 3
  for (int t = 0; t < nt2; ++t) {
    // prefetch tile t+2 (clamped dummy at the tail keeps vmcnt uniform)
    {
      int pb = c + 2; if (pb >= 3) pb -= 3;
      const int tp = (t + 2 < nt2) ? t + 2 : nt2 - 1;
      const size_t kv = (size_t)tp * 32;
      gload_lds16(kg + kv * D, KsB + pb * 2048 + t256 * 8);
      gload_lds16(vg + kv, VsB + pb * 2048 + t256 * 8);
    }
    const u16* KsC = KsB + c * 2048;
    const u16* VsC = VsB + c * 2048;
    const int gt = tb0 + t;          // global key-tile index
    const int kv0 = gt * 32;

    // --- QK(t): S^T[key][q], A = K rows (2 subtiles), B = Q (2 subtiles)
    f32x4 s[2][2];
    __builtin_amdgcn_s_setprio(1);
#pragma unroll
    for (int st = 0; st < 2; ++st) {
      const int row = st * 16 + l15;
      const bf16x8 k0 = *(const bf16x8*)(&KsC[row * 64 + ((quad ^ sw) * 8)]);
      const bf16x8 k1 = *(const bf16x8*)(&KsC[row * 64 + (((4 + quad) ^ sw) * 8)]);
#pragma unroll
      for (int qs = 0; qs < 2; ++qs) {
        s[st][qs] = mfma16(k0, qf[qs][0], zero);
        s[st][qs] = mfma16(k1, qf[qs][1], s[st][qs]);
      }
    }

    // --- PV(t-1): independent of s(t); overlaps QK in the MFMA pipe
    if (t > 0) {
#pragma unroll
      for (int nt = 0; nt < 4; ++nt)
#pragma unroll
        for (int ms = 0; ms < 2; ++ms)
          o[ms][nt] = mfma16(pf_h[ms], vf_h[nt], o[ms][nt]);
    }
    __builtin_amdgcn_s_setprio(0);

    // --- V(t) fragments into registers (independent of s)
#pragma unroll
    for (int nt = 0; nt < 4; ++nt)
      vf_h[nt] = *(const bf16x8*)(
          &VsC[(nt * 16 + l15) * 32 + ((quad ^ swv) * 8)]);

    // --- causal mask: global tile gt >= n-4 straddles the q-range
    if (gt >= n - 4) {
#pragma unroll
      for (int qs = 0; qs < 2; ++qs) {
        const int q = qb0 + qwave * 32 + qs * 16 + l15;
#pragma unroll
        for (int st = 0; st < 2; ++st)
#pragma unroll
          for (int r = 0; r < 4; ++r) {
            const int key = kv0 + st * 16 + quad * 4 + r;
            if (key > q) s[st][qs][r] = -INFINITY;
          }
      }
    }

    // --- max-free softmax: p = 2^s (Q pre-scaled by log2e); l per-lane
#pragma unroll
    for (int qs = 0; qs < 2; ++qs) {
      float sum = l_acc[qs];
#pragma unroll
      for (int st = 0; st < 2; ++st)
#pragma unroll
        for (int r = 0; r < 4; ++r) {
          const float p = __builtin_amdgcn_exp2f(s[st][qs][r]);
          s[st][qs][r] = p;
          sum += p;
        }
      l_acc[qs] = sum;
    }

    // --- P^T -> LDS (A-layout for PV), 8B vector stores, stride 40
#pragma unroll
    for (int qs = 0; qs < 2; ++qs)
#pragma unroll
      for (int st = 0; st < 2; ++st) {
        bf16x4 w;
        w[0] = (__bf16)s[st][qs][0];
        w[1] = (__bf16)s[st][qs][1];
        w[2] = (__bf16)s[st][qs][2];
        w[3] = (__bf16)s[st][qs][3];
        *(bf16x4*)(&PsW[(qs * 16 + l15) * 40 + st * 16 + quad * 4]) = w;
      }

    // --- P(t) fragments for next iteration's PV (same-wave DS is in-order)
#pragma unroll
    for (int ms = 0; ms < 2; ++ms)
      pf_h[ms] = *(const bf16x8*)(&PsW[(ms * 16 + l15) * 40 + quad * 8]);

    barrier_vm2();  // t+1 data landed; t+2 loads stay in flight
    ++c; if (c >= 3) c = 0;
  }

  // --- flush PV(last)
  __builtin_amdgcn_s_setprio(1);
#pragma unroll
  for (int nt = 0; nt < 4; ++nt)
#pragma unroll
    for (int ms = 0; ms < 2; ++ms)
      o[ms][nt] = mfma16(pf_h[ms], vf_h[nt], o[ms][nt]);
  __builtin_amdgcn_s_setprio(0);

  // --- merge halves via LDS (overlaid on K/V rings; drain async loads 1st)
  wait_vm<0>();
  __syncthreads();
  float* mo = (float*)smem;            // [4][64][32] f32 (32 KB)
  float* ml = (float*)smem + 8192;     // [4][64][2]  f32 (2 KB)
  if (half == 1) {
    float* dst = mo + (qwave * 64 + lane) * 32;
#pragma unroll
    for (int ms = 0; ms < 2; ++ms)
#pragma unroll
      for (int nt = 0; nt < 4; ++nt)
#pragma unroll
        for (int r = 0; r < 4; ++r)
          dst[ms * 16 + nt * 4 + r] = o[ms][nt][r];
    ml[(qwave * 64 + lane) * 2 + 0] = l_acc[0];
    ml[(qwave * 64 + lane) * 2 + 1] = l_acc[1];
  }
  __syncthreads();
  if (half == 1) return;
  {
    const float* src = mo + (qwave * 64 + lane) * 32;
#pragma unroll
    for (int ms = 0; ms < 2; ++ms)
#pragma unroll
      for (int nt = 0; nt < 4; ++nt)
#pragma unroll
        for (int r = 0; r < 4; ++r)
          o[ms][nt][r] += src[ms * 16 + nt * 4 + r];
    l_acc[0] += ml[(qwave * 64 + lane) * 2 + 0];
    l_acc[1] += ml[(qwave * 64 + lane) * 2 + 1];
  }

  // epilogue: reduce l across the 4 quads (once), normalize, store
#pragma unroll
  for (int ms = 0; ms < 2; ++ms) {
    float sum = l_acc[ms];
    sum += __shfl_xor(sum, 16);
    sum += __shfl_xor(sum, 32);
    const float linv = 1.0f / sum;
    float lr[4];
#pragma unroll
    for (int r = 0; r < 4; ++r) lr[r] = __shfl(linv, quad * 4 + r);
#pragma unroll
    for (int r = 0; r < 4; ++r) {
      const int qo = qb0 + qwave * 32 + ms * 16 + quad * 4 + r;
      u16* op = Ob + ((size_t)b * T + qo) * D + h * 64 + l15;
#pragma unroll
      for (int nt = 0; nt < 4; ++nt)
        op[nt * 16] = f32_bf16(o[ms][nt][r] * lr[r]);
    }
  }
}

// ---------------------------------------------------------------------------
extern "C" void kernel_launch(void* const* d_in, const int* in_sizes, int n_in,
                              void* d_out, int out_size, void* d_ws, size_t ws_size,
                              hipStream_t stream) {
  const float* x  = (const float*)d_in[0];
  const float* wq = (const float*)d_in[1];
  const float* wk = (const float*)d_in[2];
  const float* wv = (const float*)d_in[3];
  const float* wo = (const float*)d_in[4];

  const int B = 4, T = 2048, D = 1024;
  const int M = B * T;  // 8192

  u16* ws = (u16*)d_ws;
  u16* xb  = ws;                         // M*D
  u16* wqb = xb  + (size_t)M * D;        // D*D (contiguous with xb: fused cast;
  u16* wkb = wqb + (size_t)D * D;        //  wq/wk/wv contiguous -> one 3072x1024 B)
  u16* wvb = wkb + (size_t)D * D;
  u16* wob = wvb + (size_t)D * D;
  u16* Qb  = wob + (size_t)D * D;        // M*D (pre-scaled by log2e/8)
  u16* Kb  = Qb  + (size_t)M * D;
  u16* Vt  = Kb  + (size_t)M * D;        // transposed V: [bh][d][t] (from GEMM)
  u16* Ob  = Vt  + (size_t)M * D;        // attention output

  (void)wkb; (void)wvb;

  // fused cast (dst regions xb..wob are contiguous)
  const int n_x = M * D / 4, n_w = D * D / 4;
  const int n_tot = n_x + 4 * n_w;
  cvt_all_kernel<<<(n_tot + 255) / 256, 256, 0, stream>>>(x, wq, wk, wv, wo,
                                                          xb, n_x, n_w);

  // fused QKV projection: 64 row-tiles x 8 col-tiles (128x384) = 512 blocks
  // (2 exact rounds); Q scaled by (1/sqrt(Dh)) * log2(e)
  gemm8p<0><<<512, 512, 0, stream>>>(
      xb, wqb, Qb, Kb, Vt, nullptr, 0.125f * 1.44269504f);

  // flash attention: 16 q-tiles x 64 bh = 1024 blocks of 512 threads,
  // key-split halves in-block, longest blocks dispatched first
  attn_kernel<<<dim3(1024), 512, 0, stream>>>(Qb, Kb, Vt, Ob, T);

  // output projection -> fp32 d_out: 64 x 4 (128x256) = 256 blocks (1 round)
  gemm8p<1><<<256, 512, 0, stream>>>(
      Ob, wob, nullptr, nullptr, nullptr, (float*)d_out, 1.0f);
}